// Round 1
// baseline (678.623 us; speedup 1.0000x reference)
//
#include <hip/hip_runtime.h>
#include <math.h>
#include <stdint.h>

// Problem constants (B=2, T=2048, D=1024, H=16, DH=64)
#define TSEQ   2048
#define DMODEL 1024
#define NHEAD  16
#define DHEAD  64
#define MROWS  4096   // B*T

typedef short bf16x8 __attribute__((ext_vector_type(8)));
typedef float f32x4  __attribute__((ext_vector_type(4)));
typedef unsigned short u16;

typedef __attribute__((address_space(3))) unsigned int lds_u32_t;
typedef __attribute__((address_space(1))) unsigned int glb_u32_t;

static __device__ __forceinline__ u16 f2bf(float f) {
    unsigned u = __float_as_uint(f);
    u += 0x7FFFu + ((u >> 16) & 1u);   // round-to-nearest-even
    return (u16)(u >> 16);
}
static __device__ __forceinline__ float bf2f(u16 h) {
    return __uint_as_float(((unsigned)h) << 16);
}

// ---------------------------------------------------------------------------
// Transpose + cast: W[K][N] fp32  ->  Wt[N][K] bf16-bits
// ---------------------------------------------------------------------------
__global__ __launch_bounds__(256) void tc_kernel(
    const float* __restrict__ W, u16* __restrict__ Wt, int K, int N)
{
    __shared__ u16 tile[32][33];
    const int n0 = blockIdx.x * 32, k0 = blockIdx.y * 32;
    const int t = threadIdx.x;
    const int tx = t & 31, ty = t >> 5;           // 32 x 8
#pragma unroll
    for (int i = 0; i < 4; ++i) {
        int kk = ty + i * 8;
        tile[kk][tx] = f2bf(W[(size_t)(k0 + kk) * N + n0 + tx]);
    }
    __syncthreads();
#pragma unroll
    for (int i = 0; i < 4; ++i) {
        int nn = ty + i * 8;
        Wt[(size_t)(n0 + nn) * K + k0 + tx] = tile[tx][nn];
    }
}

// ---------------------------------------------------------------------------
// LayerNorm(fp32 row of 1024) -> bf16 row. One block (256 thr) per row.
// ---------------------------------------------------------------------------
__global__ __launch_bounds__(256) void ln_kernel(
    const float* __restrict__ x, const float* __restrict__ g,
    const float* __restrict__ b, u16* __restrict__ out)
{
    const int row = blockIdx.x;
    const int t = threadIdx.x;
    const float4 v = ((const float4*)(x + (size_t)row * DMODEL))[t];
    float s  = v.x + v.y + v.z + v.w;
    float s2 = v.x * v.x + v.y * v.y + v.z * v.z + v.w * v.w;
#pragma unroll
    for (int m = 32; m >= 1; m >>= 1) { s += __shfl_xor(s, m); s2 += __shfl_xor(s2, m); }
    __shared__ float ps[4], ps2[4];
    if ((t & 63) == 0) { ps[t >> 6] = s; ps2[t >> 6] = s2; }
    __syncthreads();
    const float S  = ps[0] + ps[1] + ps[2] + ps[3];
    const float S2 = ps2[0] + ps2[1] + ps2[2] + ps2[3];
    const float mean = S * (1.0f / DMODEL);
    const float var  = S2 * (1.0f / DMODEL) - mean * mean;
    const float rstd = rsqrtf(var + 1e-5f);
    const float4 gg = ((const float4*)g)[t];
    const float4 bb = ((const float4*)b)[t];
    u16 o[4];
    o[0] = f2bf((v.x - mean) * rstd * gg.x + bb.x);
    o[1] = f2bf((v.y - mean) * rstd * gg.y + bb.y);
    o[2] = f2bf((v.z - mean) * rstd * gg.z + bb.z);
    o[3] = f2bf((v.w - mean) * rstd * gg.w + bb.w);
    *(short4*)(out + (size_t)row * DMODEL + t * 4) = *(short4*)o;
}

// ---------------------------------------------------------------------------
// GEMM: C[M][N] = A[M][K] * Wt[N][K]^T (+bias) (+epilogue)
//   EPI 0: store bf16         EPI 1: exact GELU, store bf16
//   EPI 2: += resid (fp32), store fp32
// m97 structure: 128x128 tile, BK=32, 4 waves (2x2), 16x16x32 bf16 MFMA,
// global_load_lds width 16, linear LDS, 2 barriers / K-step.
// ---------------------------------------------------------------------------
template <int EPI>
__global__ __launch_bounds__(256) void gemm_bt(
    const u16* __restrict__ A, const u16* __restrict__ Wt,
    const float* __restrict__ bias, const float* __restrict__ resid,
    u16* __restrict__ Cb, float* __restrict__ Cf,
    int M, int N, int K)
{
    __shared__ __align__(16) u16 As[128 * 32];
    __shared__ __align__(16) u16 Bs[128 * 32];

    const int t = threadIdx.x;
    const int lane = t & 63;
    const int wv = t >> 6;
    const int wr = wv >> 1, wc = wv & 1;
    const int m0 = blockIdx.y * 128, n0 = blockIdx.x * 128;

    // staging addresses: granule g covers tile row g>>2, elems ((g&3)*8 ..)
    const int strow = t >> 2;            // 0..63
    const int stcol = (t & 3) * 8;
    const u16* gA  = A  + (size_t)(m0 + strow) * K + stcol;
    const u16* gA2 = gA + (size_t)64 * K;
    const u16* gB  = Wt + (size_t)(n0 + strow) * K + stcol;
    const u16* gB2 = gB + (size_t)64 * K;
    char* lA  = (char*)As + wv * 1024;
    char* lA2 = (char*)As + 4096 + wv * 1024;
    char* lB  = (char*)Bs + wv * 1024;
    char* lB2 = (char*)Bs + 4096 + wv * 1024;

    f32x4 zero = {0.f, 0.f, 0.f, 0.f};
    f32x4 acc[4][4];
#pragma unroll
    for (int mi = 0; mi < 4; ++mi)
#pragma unroll
        for (int ni = 0; ni < 4; ++ni) acc[mi][ni] = zero;

    const int fr = lane & 15, fq = lane >> 4;
    const int nk = K >> 5;
    for (int kt = 0; kt < nk; ++kt) {
        const int k0 = kt << 5;
        __builtin_amdgcn_global_load_lds((const glb_u32_t*)(gA  + k0), (lds_u32_t*)lA,  16, 0, 0);
        __builtin_amdgcn_global_load_lds((const glb_u32_t*)(gA2 + k0), (lds_u32_t*)lA2, 16, 0, 0);
        __builtin_amdgcn_global_load_lds((const glb_u32_t*)(gB  + k0), (lds_u32_t*)lB,  16, 0, 0);
        __builtin_amdgcn_global_load_lds((const glb_u32_t*)(gB2 + k0), (lds_u32_t*)lB2, 16, 0, 0);
        __syncthreads();   // drains vmcnt -> LDS tiles ready

        bf16x8 af[4], bf[4];
#pragma unroll
        for (int mi = 0; mi < 4; ++mi)
            af[mi] = *(const bf16x8*)&As[(wr * 64 + mi * 16 + fr) * 32 + fq * 8];
#pragma unroll
        for (int ni = 0; ni < 4; ++ni)
            bf[ni] = *(const bf16x8*)&Bs[(wc * 64 + ni * 16 + fr) * 32 + fq * 8];
#pragma unroll
        for (int mi = 0; mi < 4; ++mi)
#pragma unroll
            for (int ni = 0; ni < 4; ++ni)
                acc[mi][ni] = __builtin_amdgcn_mfma_f32_16x16x32_bf16(af[mi], bf[ni], acc[mi][ni], 0, 0, 0);
        __syncthreads();   // all reads done before next stage overwrites
    }

    // epilogue: C/D layout col = lane&15, row = (lane>>4)*4 + j   [m89]
#pragma unroll
    for (int ni = 0; ni < 4; ++ni) {
        const int col = n0 + wc * 64 + ni * 16 + fr;
        const float bv = bias[col];
#pragma unroll
        for (int mi = 0; mi < 4; ++mi) {
#pragma unroll
            for (int j = 0; j < 4; ++j) {
                const int row = m0 + wr * 64 + mi * 16 + fq * 4 + j;
                float val = acc[mi][ni][j] + bv;
                if (EPI == 1)
                    val = 0.5f * val * (1.0f + erff(val * 0.70710678118654752f));
                if (EPI == 2)
                    Cf[(size_t)row * N + col] = val + resid[(size_t)row * N + col];
                else
                    Cb[(size_t)row * N + col] = f2bf(val);
            }
        }
    }
}

// ---------------------------------------------------------------------------
// Banded attention: one wave per (b, h, t); lane = d. Online softmax over
// s in [t-band, t+band]. q,k,v,ctx layout: [(b*T+t)][h*64+d] bf16.
// ---------------------------------------------------------------------------
__global__ __launch_bounds__(256) void attn_kernel(
    const u16* __restrict__ q, const u16* __restrict__ k,
    const u16* __restrict__ v, u16* __restrict__ ctx,
    const int* __restrict__ band_ptr)
{
    const int band = *band_ptr;
    const int wid = blockIdx.x * 4 + (threadIdx.x >> 6);
    const int lane = threadIdx.x & 63;
    const int tq = wid & (TSEQ - 1);
    const int bh = wid >> 11;             // T = 2048
    const int h = bh & (NHEAD - 1), b = bh >> 4;
    const size_t base = (size_t)b * TSEQ * DMODEL + h * DHEAD + lane;

    const float qd = bf2f(q[base + (size_t)tq * DMODEL]) * 0.125f;  // / sqrt(64)
    const int s0 = max(0, tq - band), s1 = min(TSEQ - 1, tq + band);

    float m = -1e30f, l = 0.f, acc = 0.f;
    for (int s = s0; s <= s1; ++s) {
        float p = qd * bf2f(k[base + (size_t)s * DMODEL]);
#pragma unroll
        for (int mm = 32; mm >= 1; mm >>= 1) p += __shfl_xor(p, mm);
        const float nm = fmaxf(m, p);
        const float sc = __expf(m - nm);
        const float w  = __expf(p - nm);
        l = l * sc + w;
        acc = acc * sc + w * bf2f(v[base + (size_t)s * DMODEL]);
        m = nm;
    }
    ctx[base + (size_t)tq * DMODEL] = f2bf(acc / l);
}

// ---------------------------------------------------------------------------
extern "C" void kernel_launch(void* const* d_in, const int* in_sizes, int n_in,
                              void* d_out, int out_size, void* d_ws, size_t ws_size,
                              hipStream_t stream) {
    const float* x_ref  = (const float*)d_in[0];
    const float* x_mem  = (const float*)d_in[1];
    const float* ln_q_g = (const float*)d_in[2];
    const float* ln_q_b = (const float*)d_in[3];
    const float* ln_kv_g= (const float*)d_in[4];
    const float* ln_kv_b= (const float*)d_in[5];
    const float* Wq = (const float*)d_in[6];
    const float* bq = (const float*)d_in[7];
    const float* Wk = (const float*)d_in[8];
    const float* bk = (const float*)d_in[9];
    const float* Wv = (const float*)d_in[10];
    const float* bv = (const float*)d_in[11];
    const float* Wo = (const float*)d_in[12];
    const float* bo = (const float*)d_in[13];
    const float* ln_f_g = (const float*)d_in[14];
    const float* ln_f_b = (const float*)d_in[15];
    const float* W1 = (const float*)d_in[16];
    const float* b1 = (const float*)d_in[17];
    const float* W2 = (const float*)d_in[18];
    const float* b2 = (const float*)d_in[19];
    const int*  band = (const int*)d_in[20];
    float* out = (float*)d_out;

    char* ws = (char*)d_ws;
    const size_t MB = 1024 * 1024;
    if (ws_size < 128 * MB) return;   // not enough scratch -> fail visibly
    u16*   wt_q = (u16*)(ws + 0 * MB);    // [1024][1024]
    u16*   wt_k = (u16*)(ws + 2 * MB);
    u16*   wt_v = (u16*)(ws + 4 * MB);
    u16*   wt_o = (u16*)(ws + 6 * MB);
    u16*   wt_1 = (u16*)(ws + 8 * MB);    // [4096][1024]
    u16*   wt_2 = (u16*)(ws + 16 * MB);   // [1024][4096]
    u16*   aq   = (u16*)(ws + 24 * MB);   // LN(x_refined) bf16 [4096][1024]
    u16*   akv  = (u16*)(ws + 32 * MB);
    u16*   qb   = (u16*)(ws + 40 * MB);
    u16*   kb   = (u16*)(ws + 48 * MB);
    u16*   vb   = (u16*)(ws + 56 * MB);
    u16*   ctxb = (u16*)(ws + 64 * MB);
    float* y    = (float*)(ws + 72 * MB); // fp32 [4096][1024]
    u16*   hb   = (u16*)(ws + 88 * MB);
    u16*   a1   = (u16*)(ws + 96 * MB);   // [4096][4096] bf16

    dim3 blk(256);
    // weight transpose-casts
    tc_kernel<<<dim3(32, 32),  blk, 0, stream>>>(Wq, wt_q, 1024, 1024);
    tc_kernel<<<dim3(32, 32),  blk, 0, stream>>>(Wk, wt_k, 1024, 1024);
    tc_kernel<<<dim3(32, 32),  blk, 0, stream>>>(Wv, wt_v, 1024, 1024);
    tc_kernel<<<dim3(32, 32),  blk, 0, stream>>>(Wo, wt_o, 1024, 1024);
    tc_kernel<<<dim3(128, 32), blk, 0, stream>>>(W1, wt_1, 1024, 4096);
    tc_kernel<<<dim3(32, 128), blk, 0, stream>>>(W2, wt_2, 4096, 1024);
    // LayerNorms -> bf16
    ln_kernel<<<MROWS, blk, 0, stream>>>(x_ref, ln_q_g, ln_q_b, aq);
    ln_kernel<<<MROWS, blk, 0, stream>>>(x_mem, ln_kv_g, ln_kv_b, akv);
    // QKV projections
    gemm_bt<0><<<dim3(8, 32), blk, 0, stream>>>(aq,  wt_q, bq, nullptr, qb, nullptr, MROWS, 1024, 1024);
    gemm_bt<0><<<dim3(8, 32), blk, 0, stream>>>(akv, wt_k, bk, nullptr, kb, nullptr, MROWS, 1024, 1024);
    gemm_bt<0><<<dim3(8, 32), blk, 0, stream>>>(akv, wt_v, bv, nullptr, vb, nullptr, MROWS, 1024, 1024);
    // banded attention
    attn_kernel<<<MROWS * NHEAD / 4, blk, 0, stream>>>(qb, kb, vb, ctxb, band);
    // y = x_refined + ctx @ Wo + bo   (fp32)
    gemm_bt<2><<<dim3(8, 32), blk, 0, stream>>>(ctxb, wt_o, bo, x_ref, nullptr, y, MROWS, 1024, 1024);
    // LN_f(y) -> bf16
    ln_kernel<<<MROWS, blk, 0, stream>>>(y, ln_f_g, ln_f_b, hb);
    // FFN
    gemm_bt<1><<<dim3(32, 32), blk, 0, stream>>>(hb, wt_1, b1, nullptr, a1, nullptr, MROWS, 4096, 1024);
    gemm_bt<2><<<dim3(8, 32),  blk, 0, stream>>>(a1, wt_2, b2, y, nullptr, out, MROWS, 1024, 4096);
}

// Round 2
// 474.197 us; speedup vs baseline: 1.4311x; 1.4311x over previous
//
#include <hip/hip_runtime.h>
#include <math.h>
#include <stdint.h>

// Problem constants (B=2, T=2048, D=1024, H=16, DH=64)
#define TSEQ   2048
#define DMODEL 1024
#define NHEAD  16
#define DHEAD  64
#define MROWS  4096   // B*T

typedef short bf16x8 __attribute__((ext_vector_type(8)));
typedef float f32x4  __attribute__((ext_vector_type(4)));
typedef unsigned short u16;

typedef __attribute__((address_space(3))) unsigned int lds_u32_t;
typedef __attribute__((address_space(1))) unsigned int glb_u32_t;

static __device__ __forceinline__ u16 f2bf(float f) {
    unsigned u = __float_as_uint(f);
    u += 0x7FFFu + ((u >> 16) & 1u);   // round-to-nearest-even
    return (u16)(u >> 16);
}
static __device__ __forceinline__ float bf2f(u16 h) {
    return __uint_as_float(((unsigned)h) << 16);
}

// ---------------------------------------------------------------------------
// Transpose + cast: W[K][N] fp32  ->  Wt[N][K] bf16-bits
// ---------------------------------------------------------------------------
__global__ __launch_bounds__(256) void tc_kernel(
    const float* __restrict__ W, u16* __restrict__ Wt, int K, int N)
{
    __shared__ u16 tile[32][33];
    const int n0 = blockIdx.x * 32, k0 = blockIdx.y * 32;
    const int t = threadIdx.x;
    const int tx = t & 31, ty = t >> 5;           // 32 x 8
#pragma unroll
    for (int i = 0; i < 4; ++i) {
        int kk = ty + i * 8;
        tile[kk][tx] = f2bf(W[(size_t)(k0 + kk) * N + n0 + tx]);
    }
    __syncthreads();
#pragma unroll
    for (int i = 0; i < 4; ++i) {
        int nn = ty + i * 8;
        Wt[(size_t)(n0 + nn) * K + k0 + tx] = tile[tx][nn];
    }
}

// ---------------------------------------------------------------------------
// bf16 transpose: v[b*T + t][h*64 + d] -> vT[(b*16+h)*64 + d][t]
// 64x64 tiles per block.
// ---------------------------------------------------------------------------
__global__ __launch_bounds__(256) void vt_kernel(
    const u16* __restrict__ v, u16* __restrict__ vT)
{
    __shared__ __align__(16) u16 tile[64][72];
    const int bb = blockIdx.z;
    const int t0 = blockIdx.x * 64;
    const int c0 = blockIdx.y * 64;     // hd
    const int tid = threadIdx.x;
    const int r = tid >> 2;             // 0..63
    const int c = (tid & 3) * 16;       // 0,16,32,48
    const u16* src = v + (size_t)(bb * TSEQ + t0 + r) * DMODEL + c0 + c;
    *(bf16x8*)&tile[r][c]     = *(const bf16x8*)(src);
    *(bf16x8*)&tile[r][c + 8] = *(const bf16x8*)(src + 8);
    __syncthreads();
    u16 o[16];
#pragma unroll
    for (int j = 0; j < 16; ++j) o[j] = tile[c + j][r];
    u16* dst = vT + (size_t)(bb * 1024 + c0 + r) * TSEQ + t0 + c;
    *(bf16x8*)dst       = *(bf16x8*)&o[0];
    *(bf16x8*)(dst + 8) = *(bf16x8*)&o[8];
}

// ---------------------------------------------------------------------------
// LayerNorm(fp32 row of 1024) -> bf16 row. One block (256 thr) per row.
// ---------------------------------------------------------------------------
__global__ __launch_bounds__(256) void ln_kernel(
    const float* __restrict__ x, const float* __restrict__ g,
    const float* __restrict__ b, u16* __restrict__ out)
{
    const int row = blockIdx.x;
    const int t = threadIdx.x;
    const float4 v = ((const float4*)(x + (size_t)row * DMODEL))[t];
    float s  = v.x + v.y + v.z + v.w;
    float s2 = v.x * v.x + v.y * v.y + v.z * v.z + v.w * v.w;
#pragma unroll
    for (int m = 32; m >= 1; m >>= 1) { s += __shfl_xor(s, m); s2 += __shfl_xor(s2, m); }
    __shared__ float ps[4], ps2[4];
    if ((t & 63) == 0) { ps[t >> 6] = s; ps2[t >> 6] = s2; }
    __syncthreads();
    const float S  = ps[0] + ps[1] + ps[2] + ps[3];
    const float S2 = ps2[0] + ps2[1] + ps2[2] + ps2[3];
    const float mean = S * (1.0f / DMODEL);
    const float var  = S2 * (1.0f / DMODEL) - mean * mean;
    const float rstd = rsqrtf(var + 1e-5f);
    const float4 gg = ((const float4*)g)[t];
    const float4 bb = ((const float4*)b)[t];
    u16 o[4];
    o[0] = f2bf((v.x - mean) * rstd * gg.x + bb.x);
    o[1] = f2bf((v.y - mean) * rstd * gg.y + bb.y);
    o[2] = f2bf((v.z - mean) * rstd * gg.z + bb.z);
    o[3] = f2bf((v.w - mean) * rstd * gg.w + bb.w);
    *(short4*)(out + (size_t)row * DMODEL + t * 4) = *(short4*)o;
}

// ---------------------------------------------------------------------------
// GEMM: C[M][N] = A[M][K] * Wt[N][K]^T (+bias) (+epilogue)
//   EPI 0: store bf16         EPI 1: exact GELU, store bf16
//   EPI 2: += resid (fp32), store fp32
// ---------------------------------------------------------------------------
template <int EPI>
__global__ __launch_bounds__(256) void gemm_bt(
    const u16* __restrict__ A, const u16* __restrict__ Wt,
    const float* __restrict__ bias, const float* __restrict__ resid,
    u16* __restrict__ Cb, float* __restrict__ Cf,
    int M, int N, int K)
{
    __shared__ __align__(16) u16 As[128 * 32];
    __shared__ __align__(16) u16 Bs[128 * 32];

    const int t = threadIdx.x;
    const int lane = t & 63;
    const int wv = t >> 6;
    const int wr = wv >> 1, wc = wv & 1;
    const int m0 = blockIdx.y * 128, n0 = blockIdx.x * 128;

    const int strow = t >> 2;            // 0..63
    const int stcol = (t & 3) * 8;
    const u16* gA  = A  + (size_t)(m0 + strow) * K + stcol;
    const u16* gA2 = gA + (size_t)64 * K;
    const u16* gB  = Wt + (size_t)(n0 + strow) * K + stcol;
    const u16* gB2 = gB + (size_t)64 * K;
    char* lA  = (char*)As + wv * 1024;
    char* lA2 = (char*)As + 4096 + wv * 1024;
    char* lB  = (char*)Bs + wv * 1024;
    char* lB2 = (char*)Bs + 4096 + wv * 1024;

    f32x4 zero = {0.f, 0.f, 0.f, 0.f};
    f32x4 acc[4][4];
#pragma unroll
    for (int mi = 0; mi < 4; ++mi)
#pragma unroll
        for (int ni = 0; ni < 4; ++ni) acc[mi][ni] = zero;

    const int fr = lane & 15, fq = lane >> 4;
    const int nk = K >> 5;
    for (int kt = 0; kt < nk; ++kt) {
        const int k0 = kt << 5;
        __builtin_amdgcn_global_load_lds((const glb_u32_t*)(gA  + k0), (lds_u32_t*)lA,  16, 0, 0);
        __builtin_amdgcn_global_load_lds((const glb_u32_t*)(gA2 + k0), (lds_u32_t*)lA2, 16, 0, 0);
        __builtin_amdgcn_global_load_lds((const glb_u32_t*)(gB  + k0), (lds_u32_t*)lB,  16, 0, 0);
        __builtin_amdgcn_global_load_lds((const glb_u32_t*)(gB2 + k0), (lds_u32_t*)lB2, 16, 0, 0);
        __syncthreads();

        bf16x8 af[4], bfr[4];
#pragma unroll
        for (int mi = 0; mi < 4; ++mi)
            af[mi] = *(const bf16x8*)&As[(wr * 64 + mi * 16 + fr) * 32 + fq * 8];
#pragma unroll
        for (int ni = 0; ni < 4; ++ni)
            bfr[ni] = *(const bf16x8*)&Bs[(wc * 64 + ni * 16 + fr) * 32 + fq * 8];
#pragma unroll
        for (int mi = 0; mi < 4; ++mi)
#pragma unroll
            for (int ni = 0; ni < 4; ++ni)
                acc[mi][ni] = __builtin_amdgcn_mfma_f32_16x16x32_bf16(af[mi], bfr[ni], acc[mi][ni], 0, 0, 0);
        __syncthreads();
    }

#pragma unroll
    for (int ni = 0; ni < 4; ++ni) {
        const int col = n0 + wc * 64 + ni * 16 + fr;
        const float bv = bias[col];
#pragma unroll
        for (int mi = 0; mi < 4; ++mi) {
#pragma unroll
            for (int j = 0; j < 4; ++j) {
                const int row = m0 + wr * 64 + mi * 16 + fq * 4 + j;
                float val = acc[mi][ni][j] + bv;
                if (EPI == 1)
                    val = 0.5f * val * (1.0f + erff(val * 0.70710678118654752f));
                if (EPI == 2)
                    Cf[(size_t)row * N + col] = val + resid[(size_t)row * N + col];
                else
                    Cb[(size_t)row * N + col] = f2bf(val);
            }
        }
    }
}

// ---------------------------------------------------------------------------
// Banded attention via MFMA. One wave = 16 queries x 80-key aligned window
// (supports band <= 32). Block = 4 waves = 64 consecutive queries of one
// (b,h). Single-pass masked softmax: scores in C-layout (col=key, row=query)
// -> 8 shuffle-reduces per 16 queries. P reshaped through per-wave LDS into
// A-frags; PV uses V^T fragments (contiguous 16B loads).
// ---------------------------------------------------------------------------
__global__ __launch_bounds__(256) void battn_kernel(
    const u16* __restrict__ q, const u16* __restrict__ k,
    const u16* __restrict__ vT, u16* __restrict__ ctx,
    const int* __restrict__ band_ptr)
{
    __shared__ __align__(16) u16 P[4][16][104];
    const int band = *band_ptr;
    const int bid = blockIdx.x;
    const int tile = bid & 31;
    const int h = (bid >> 5) & 15;
    const int b = bid >> 9;
    const int w = threadIdx.x >> 6;
    const int lane = threadIdx.x & 63;
    const int fr = lane & 15, fq = lane >> 4;
    const int t0 = tile * 64 + w * 16;

    const size_t qkbase = ((size_t)b * TSEQ) * DMODEL + h * DHEAD;

    // Q fragments (A-operand): lane fr = query row, elems d = chunk*32 + fq*8
    const bf16x8 aq0 = *(const bf16x8*)&q[qkbase + (size_t)(t0 + fr) * DMODEL + fq * 8];
    const bf16x8 aq1 = *(const bf16x8*)&q[qkbase + (size_t)(t0 + fr) * DMODEL + 32 + fq * 8];

    const int kb0 = t0 - 32;
    const f32x4 zero = {0.f, 0.f, 0.f, 0.f};

    // QK^T: 5 key tiles x 2 d-chunks
    f32x4 sc[5];
#pragma unroll
    for (int kt = 0; kt < 5; ++kt) {
        const int srow = kb0 + kt * 16 + fr;
        const int scl = min(max(srow, 0), TSEQ - 1);
        const bf16x8 kf0 = *(const bf16x8*)&k[qkbase + (size_t)scl * DMODEL + fq * 8];
        const bf16x8 kf1 = *(const bf16x8*)&k[qkbase + (size_t)scl * DMODEL + 32 + fq * 8];
        f32x4 a = zero;
        a = __builtin_amdgcn_mfma_f32_16x16x32_bf16(aq0, kf0, a, 0, 0, 0);
        a = __builtin_amdgcn_mfma_f32_16x16x32_bf16(aq1, kf1, a, 0, 0, 0);
        sc[kt] = a;
    }

    // mask + scale + row-max
    float mx[4], l[4];
#pragma unroll
    for (int j = 0; j < 4; ++j) mx[j] = -1e30f;
#pragma unroll
    for (int kt = 0; kt < 5; ++kt) {
        const int s = kb0 + kt * 16 + fr;
#pragma unroll
        for (int j = 0; j < 4; ++j) {
            const int tq = t0 + fq * 4 + j;
            const bool ok = (s >= 0) && (s < TSEQ) && (abs(tq - s) <= band);
            const float vv = ok ? sc[kt][j] * 0.125f : -1e30f;
            sc[kt][j] = vv;
            mx[j] = fmaxf(mx[j], vv);
        }
    }
#pragma unroll
    for (int m = 1; m <= 8; m <<= 1)
#pragma unroll
        for (int j = 0; j < 4; ++j) mx[j] = fmaxf(mx[j], __shfl_xor(mx[j], m));

    // exp + row-sum
#pragma unroll
    for (int j = 0; j < 4; ++j) l[j] = 0.f;
#pragma unroll
    for (int kt = 0; kt < 5; ++kt)
#pragma unroll
        for (int j = 0; j < 4; ++j) {
            const float p = __expf(sc[kt][j] - mx[j]);   // masked -> exp(-huge)=0
            sc[kt][j] = p;
            l[j] += p;
        }
#pragma unroll
    for (int m = 1; m <= 8; m <<= 1)
#pragma unroll
        for (int j = 0; j < 4; ++j) l[j] += __shfl_xor(l[j], m);

    // P -> LDS (bf16), pad cols 80..95 with zeros
#pragma unroll
    for (int kt = 0; kt < 5; ++kt)
#pragma unroll
        for (int j = 0; j < 4; ++j)
            P[w][fq * 4 + j][kt * 16 + fr] = f2bf(sc[kt][j]);
    {
        const short4 z4 = {0, 0, 0, 0};
        *(short4*)&P[w][fr][80 + fq * 4] = z4;
    }
    __syncthreads();

    // PV: A = P (lane fr = query row, elems s = c*32 + fq*8); B = vT rows (d)
    bf16x8 pa[3];
#pragma unroll
    for (int c = 0; c < 3; ++c)
        pa[c] = *(const bf16x8*)&P[w][fr][c * 32 + fq * 8];

    const size_t vbase = ((size_t)(b * NHEAD + h) * DHEAD) * TSEQ;
    f32x4 cacc[4];
#pragma unroll
    for (int dt = 0; dt < 4; ++dt) cacc[dt] = zero;
#pragma unroll
    for (int dt = 0; dt < 4; ++dt) {
#pragma unroll
        for (int c = 0; c < 3; ++c) {
            const int s8 = kb0 + c * 32 + fq * 8;
            const int s8c = min(max(s8, 0), TSEQ - 8);
            const bf16x8 vf = *(const bf16x8*)&vT[vbase + (size_t)(dt * 16 + fr) * TSEQ + s8c];
            cacc[dt] = __builtin_amdgcn_mfma_f32_16x16x32_bf16(pa[c], vf, cacc[dt], 0, 0, 0);
        }
    }

    float rl[4];
#pragma unroll
    for (int j = 0; j < 4; ++j) rl[j] = 1.0f / l[j];
#pragma unroll
    for (int dt = 0; dt < 4; ++dt)
#pragma unroll
        for (int j = 0; j < 4; ++j)
            ctx[qkbase + (size_t)(t0 + fq * 4 + j) * DMODEL + dt * 16 + fr] =
                f2bf(cacc[dt][j] * rl[j]);
}

// ---------------------------------------------------------------------------
extern "C" void kernel_launch(void* const* d_in, const int* in_sizes, int n_in,
                              void* d_out, int out_size, void* d_ws, size_t ws_size,
                              hipStream_t stream) {
    const float* x_ref  = (const float*)d_in[0];
    const float* x_mem  = (const float*)d_in[1];
    const float* ln_q_g = (const float*)d_in[2];
    const float* ln_q_b = (const float*)d_in[3];
    const float* ln_kv_g= (const float*)d_in[4];
    const float* ln_kv_b= (const float*)d_in[5];
    const float* Wq = (const float*)d_in[6];
    const float* bq = (const float*)d_in[7];
    const float* Wk = (const float*)d_in[8];
    const float* bk = (const float*)d_in[9];
    const float* Wv = (const float*)d_in[10];
    const float* bv = (const float*)d_in[11];
    const float* Wo = (const float*)d_in[12];
    const float* bo = (const float*)d_in[13];
    const float* ln_f_g = (const float*)d_in[14];
    const float* ln_f_b = (const float*)d_in[15];
    const float* W1 = (const float*)d_in[16];
    const float* b1 = (const float*)d_in[17];
    const float* W2 = (const float*)d_in[18];
    const float* b2 = (const float*)d_in[19];
    const int*  band = (const int*)d_in[20];
    float* out = (float*)d_out;

    char* ws = (char*)d_ws;
    const size_t MB = 1024 * 1024;
    if (ws_size < 128 * MB) return;
    u16*   wt_q = (u16*)(ws + 0 * MB);
    u16*   wt_k = (u16*)(ws + 2 * MB);
    u16*   wt_v = (u16*)(ws + 4 * MB);
    u16*   wt_o = (u16*)(ws + 6 * MB);
    u16*   wt_1 = (u16*)(ws + 8 * MB);
    u16*   wt_2 = (u16*)(ws + 16 * MB);
    u16*   aq   = (u16*)(ws + 24 * MB);   // reused as vT after Q-proj
    u16*   akv  = (u16*)(ws + 32 * MB);
    u16*   qb   = (u16*)(ws + 40 * MB);
    u16*   kb   = (u16*)(ws + 48 * MB);
    u16*   vb   = (u16*)(ws + 56 * MB);
    u16*   ctxb = (u16*)(ws + 64 * MB);
    float* y    = (float*)(ws + 72 * MB);
    u16*   hb   = (u16*)(ws + 88 * MB);
    u16*   a1   = (u16*)(ws + 96 * MB);
    u16*   vTb  = aq;                     // [2048 (b,h,d)][2048 t] bf16 = 8 MB

    dim3 blk(256);
    tc_kernel<<<dim3(32, 32),  blk, 0, stream>>>(Wq, wt_q, 1024, 1024);
    tc_kernel<<<dim3(32, 32),  blk, 0, stream>>>(Wk, wt_k, 1024, 1024);
    tc_kernel<<<dim3(32, 32),  blk, 0, stream>>>(Wv, wt_v, 1024, 1024);
    tc_kernel<<<dim3(32, 32),  blk, 0, stream>>>(Wo, wt_o, 1024, 1024);
    tc_kernel<<<dim3(128, 32), blk, 0, stream>>>(W1, wt_1, 1024, 4096);
    tc_kernel<<<dim3(32, 128), blk, 0, stream>>>(W2, wt_2, 4096, 1024);
    ln_kernel<<<MROWS, blk, 0, stream>>>(x_ref, ln_q_g, ln_q_b, aq);
    ln_kernel<<<MROWS, blk, 0, stream>>>(x_mem, ln_kv_g, ln_kv_b, akv);
    // QKV projections (Q first: frees aq for reuse as vT)
    gemm_bt<0><<<dim3(8, 32), blk, 0, stream>>>(aq,  wt_q, bq, nullptr, qb, nullptr, MROWS, 1024, 1024);
    gemm_bt<0><<<dim3(8, 32), blk, 0, stream>>>(akv, wt_k, bk, nullptr, kb, nullptr, MROWS, 1024, 1024);
    gemm_bt<0><<<dim3(8, 32), blk, 0, stream>>>(akv, wt_v, bv, nullptr, vb, nullptr, MROWS, 1024, 1024);
    // V transpose for PV fragments
    vt_kernel<<<dim3(32, 16, 2), blk, 0, stream>>>(vb, vTb);
    // banded MFMA attention
    battn_kernel<<<1024, blk, 0, stream>>>(qb, kb, vTb, ctxb, band);
    // y = x_refined + ctx @ Wo + bo   (fp32)
    gemm_bt<2><<<dim3(8, 32), blk, 0, stream>>>(ctxb, wt_o, bo, x_ref, nullptr, y, MROWS, 1024, 1024);
    ln_kernel<<<MROWS, blk, 0, stream>>>(y, ln_f_g, ln_f_b, hb);
    gemm_bt<1><<<dim3(32, 32), blk, 0, stream>>>(hb, wt_1, b1, nullptr, a1, nullptr, MROWS, 4096, 1024);
    gemm_bt<2><<<dim3(8, 32),  blk, 0, stream>>>(a1, wt_2, b2, y, nullptr, out, MROWS, 1024, 4096);
}

// Round 3
// 408.213 us; speedup vs baseline: 1.6624x; 1.1616x over previous
//
#include <hip/hip_runtime.h>
#include <math.h>
#include <stdint.h>

// Problem constants (B=2, T=2048, D=1024, H=16, DH=64)
#define TSEQ   2048
#define DMODEL 1024
#define NHEAD  16
#define DHEAD  64
#define MROWS  4096   // B*T

typedef short bf16x8 __attribute__((ext_vector_type(8)));
typedef float f32x4  __attribute__((ext_vector_type(4)));
typedef unsigned short u16;

typedef __attribute__((address_space(3))) unsigned int lds_u32_t;
typedef __attribute__((address_space(1))) unsigned int glb_u32_t;

static __device__ __forceinline__ u16 f2bf(float f) {
    unsigned u = __float_as_uint(f);
    u += 0x7FFFu + ((u >> 16) & 1u);   // round-to-nearest-even
    return (u16)(u >> 16);
}
static __device__ __forceinline__ float bf2f(u16 h) {
    return __uint_as_float(((unsigned)h) << 16);
}

// ---------------------------------------------------------------------------
// Transpose + cast: W[K][N] fp32  ->  Wt[N][K] bf16-bits
// ---------------------------------------------------------------------------
__global__ __launch_bounds__(256) void tc_kernel(
    const float* __restrict__ W, u16* __restrict__ Wt, int K, int N)
{
    __shared__ u16 tile[32][33];
    const int n0 = blockIdx.x * 32, k0 = blockIdx.y * 32;
    const int t = threadIdx.x;
    const int tx = t & 31, ty = t >> 5;           // 32 x 8
#pragma unroll
    for (int i = 0; i < 4; ++i) {
        int kk = ty + i * 8;
        tile[kk][tx] = f2bf(W[(size_t)(k0 + kk) * N + n0 + tx]);
    }
    __syncthreads();
#pragma unroll
    for (int i = 0; i < 4; ++i) {
        int nn = ty + i * 8;
        Wt[(size_t)(n0 + nn) * K + k0 + tx] = tile[tx][nn];
    }
}

// ---------------------------------------------------------------------------
// Pack 3 bias vectors (1024 each) into one 3072 fp32 vector
// ---------------------------------------------------------------------------
__global__ __launch_bounds__(256) void biaspack_kernel(
    const float* __restrict__ bq, const float* __restrict__ bk,
    const float* __restrict__ bv, float* __restrict__ o)
{
    const int i = blockIdx.x * 256 + threadIdx.x;
    if (i < 1024) o[i] = bq[i];
    else if (i < 2048) o[i] = bk[i - 1024];
    else if (i < 3072) o[i] = bv[i - 2048];
}

// ---------------------------------------------------------------------------
// bf16 transpose of V section: qkv[b*T + t][2048 + hd] -> vT[(b*16+h)*64+d][t]
// ---------------------------------------------------------------------------
__global__ __launch_bounds__(256) void vt_kernel(
    const u16* __restrict__ qkv, u16* __restrict__ vT)
{
    __shared__ __align__(16) u16 tile[64][72];
    const int bb = blockIdx.z;
    const int t0 = blockIdx.x * 64;
    const int c0 = blockIdx.y * 64;     // hd
    const int tid = threadIdx.x;
    const int r = tid >> 2;             // 0..63
    const int c = (tid & 3) * 16;       // 0,16,32,48
    const u16* src = qkv + (size_t)(bb * TSEQ + t0 + r) * 3072 + 2048 + c0 + c;
    *(bf16x8*)&tile[r][c]     = *(const bf16x8*)(src);
    *(bf16x8*)&tile[r][c + 8] = *(const bf16x8*)(src + 8);
    __syncthreads();
    u16 o[16];
#pragma unroll
    for (int j = 0; j < 16; ++j) o[j] = tile[c + j][r];
    u16* dst = vT + (size_t)(bb * 1024 + c0 + r) * TSEQ + t0 + c;
    *(bf16x8*)dst       = *(bf16x8*)&o[0];
    *(bf16x8*)(dst + 8) = *(bf16x8*)&o[8];
}

// ---------------------------------------------------------------------------
// LayerNorm(fp32 row of 1024) -> bf16 row. One block (256 thr) per row.
// ---------------------------------------------------------------------------
__global__ __launch_bounds__(256) void ln_kernel(
    const float* __restrict__ x, const float* __restrict__ g,
    const float* __restrict__ b, u16* __restrict__ out)
{
    const int row = blockIdx.x;
    const int t = threadIdx.x;
    const float4 v = ((const float4*)(x + (size_t)row * DMODEL))[t];
    float s  = v.x + v.y + v.z + v.w;
    float s2 = v.x * v.x + v.y * v.y + v.z * v.z + v.w * v.w;
#pragma unroll
    for (int m = 32; m >= 1; m >>= 1) { s += __shfl_xor(s, m); s2 += __shfl_xor(s2, m); }
    __shared__ float ps[4], ps2[4];
    if ((t & 63) == 0) { ps[t >> 6] = s; ps2[t >> 6] = s2; }
    __syncthreads();
    const float S  = ps[0] + ps[1] + ps[2] + ps[3];
    const float S2 = ps2[0] + ps2[1] + ps2[2] + ps2[3];
    const float mean = S * (1.0f / DMODEL);
    const float var  = S2 * (1.0f / DMODEL) - mean * mean;
    const float rstd = rsqrtf(var + 1e-5f);
    const float4 gg = ((const float4*)g)[t];
    const float4 bb = ((const float4*)b)[t];
    u16 o[4];
    o[0] = f2bf((v.x - mean) * rstd * gg.x + bb.x);
    o[1] = f2bf((v.y - mean) * rstd * gg.y + bb.y);
    o[2] = f2bf((v.z - mean) * rstd * gg.z + bb.z);
    o[3] = f2bf((v.w - mean) * rstd * gg.w + bb.w);
    *(short4*)(out + (size_t)row * DMODEL + t * 4) = *(short4*)o;
}

// ---------------------------------------------------------------------------
// GEMM: C[M][N] = A[M][K] * Wt[N][K]^T (+bias) (+epilogue)
//   EPI 0: +bias, store bf16       EPI 1: +bias, exact GELU, store bf16
//   EPI 2: +bias, += resid (fp32), store fp32
//   EPI 3: split-K partial, no bias, fp32 to (blockIdx.y ? Cf2 : Cf)
// 1-D grid x (tiles, XCD-swizzled; requires nwg%8==0), grid y = K-split.
// A2 (if non-null) is used for output cols >= 1024 (fused QKV).
// ---------------------------------------------------------------------------
template <int EPI>
__global__ __launch_bounds__(256) void gemm_bt(
    const u16* __restrict__ A, const u16* __restrict__ A2,
    const u16* __restrict__ Wt,
    const float* __restrict__ bias, const float* __restrict__ resid,
    u16* __restrict__ Cb, float* __restrict__ Cf, float* __restrict__ Cf2,
    int M, int N, int K, int kl, int gx)
{
    __shared__ __align__(16) u16 As[128 * 32];
    __shared__ __align__(16) u16 Bs[128 * 32];

    // bijective XCD swizzle over the 1-D tile grid
    const int nwg = gridDim.x;
    const int bid = blockIdx.x;
    const int swz = (bid & 7) * (nwg >> 3) + (bid >> 3);
    const int bx = swz % gx, by = swz / gx;
    const int m0 = by * 128, n0 = bx * 128;
    const int kofs = blockIdx.y * kl;

    const int t = threadIdx.x;
    const int lane = t & 63;
    const int wv = t >> 6;
    const int wr = wv >> 1, wc = wv & 1;

    const u16* Ause = (A2 != nullptr && n0 >= 1024) ? A2 : A;

    const int strow = t >> 2;            // 0..63
    const int stcol = (t & 3) * 8;
    const u16* gA  = Ause + (size_t)(m0 + strow) * K + kofs + stcol;
    const u16* gA2 = gA + (size_t)64 * K;
    const u16* gB  = Wt + (size_t)(n0 + strow) * K + kofs + stcol;
    const u16* gB2 = gB + (size_t)64 * K;
    char* lA  = (char*)As + wv * 1024;
    char* lA2 = (char*)As + 4096 + wv * 1024;
    char* lB  = (char*)Bs + wv * 1024;
    char* lB2 = (char*)Bs + 4096 + wv * 1024;

    f32x4 zero = {0.f, 0.f, 0.f, 0.f};
    f32x4 acc[4][4];
#pragma unroll
    for (int mi = 0; mi < 4; ++mi)
#pragma unroll
        for (int ni = 0; ni < 4; ++ni) acc[mi][ni] = zero;

    const int fr = lane & 15, fq = lane >> 4;
    const int nk = kl >> 5;
    for (int kt = 0; kt < nk; ++kt) {
        const int k0 = kt << 5;
        __builtin_amdgcn_global_load_lds((const glb_u32_t*)(gA  + k0), (lds_u32_t*)lA,  16, 0, 0);
        __builtin_amdgcn_global_load_lds((const glb_u32_t*)(gA2 + k0), (lds_u32_t*)lA2, 16, 0, 0);
        __builtin_amdgcn_global_load_lds((const glb_u32_t*)(gB  + k0), (lds_u32_t*)lB,  16, 0, 0);
        __builtin_amdgcn_global_load_lds((const glb_u32_t*)(gB2 + k0), (lds_u32_t*)lB2, 16, 0, 0);
        __syncthreads();

        bf16x8 af[4], bfr[4];
#pragma unroll
        for (int mi = 0; mi < 4; ++mi)
            af[mi] = *(const bf16x8*)&As[(wr * 64 + mi * 16 + fr) * 32 + fq * 8];
#pragma unroll
        for (int ni = 0; ni < 4; ++ni)
            bfr[ni] = *(const bf16x8*)&Bs[(wc * 64 + ni * 16 + fr) * 32 + fq * 8];
#pragma unroll
        for (int mi = 0; mi < 4; ++mi)
#pragma unroll
            for (int ni = 0; ni < 4; ++ni)
                acc[mi][ni] = __builtin_amdgcn_mfma_f32_16x16x32_bf16(af[mi], bfr[ni], acc[mi][ni], 0, 0, 0);
        __syncthreads();
    }

    float* Cpart = (EPI == 3) ? (blockIdx.y ? Cf2 : Cf) : Cf;
#pragma unroll
    for (int ni = 0; ni < 4; ++ni) {
        const int col = n0 + wc * 64 + ni * 16 + fr;
        const float bv = (EPI == 3) ? 0.f : bias[col];
#pragma unroll
        for (int mi = 0; mi < 4; ++mi) {
#pragma unroll
            for (int j = 0; j < 4; ++j) {
                const int row = m0 + wr * 64 + mi * 16 + fq * 4 + j;
                float val = acc[mi][ni][j] + bv;
                if (EPI == 1)
                    val = 0.5f * val * (1.0f + erff(val * 0.70710678118654752f));
                if (EPI == 2)
                    Cf[(size_t)row * N + col] = val + resid[(size_t)row * N + col];
                else if (EPI == 3)
                    Cpart[(size_t)row * N + col] = val;
                else
                    Cb[(size_t)row * N + col] = f2bf(val);
            }
        }
    }
}

// ---------------------------------------------------------------------------
// Split-K reduce: out = p0 + p1 + bias + resid  (fp32, vectorized)
// ---------------------------------------------------------------------------
__global__ __launch_bounds__(256) void redk_kernel(
    const float* __restrict__ p0, const float* __restrict__ p1,
    const float* __restrict__ bias, const float* __restrict__ resid,
    float* __restrict__ out, int n4, int ncols)
{
    const int stride = gridDim.x * 256;
    for (int i = blockIdx.x * 256 + threadIdx.x; i < n4; i += stride) {
        const float4 a = ((const float4*)p0)[i];
        const float4 b = ((const float4*)p1)[i];
        const float4 r = ((const float4*)resid)[i];
        const float4 bb = *(const float4*)&bias[(i * 4) & (ncols - 1)];
        float4 o;
        o.x = a.x + b.x + bb.x + r.x;
        o.y = a.y + b.y + bb.y + r.y;
        o.z = a.z + b.z + bb.z + r.z;
        o.w = a.w + b.w + bb.w + r.w;
        ((float4*)out)[i] = o;
    }
}

// ---------------------------------------------------------------------------
// Banded attention via MFMA. One wave = 16 queries x 80-key aligned window
// (supports band <= 32). q,k read from fused qkv [4096][3072]; ctx -> [4096][1024].
// ---------------------------------------------------------------------------
__global__ __launch_bounds__(256) void battn_kernel(
    const u16* __restrict__ qkv, const u16* __restrict__ vT,
    u16* __restrict__ ctx, const int* __restrict__ band_ptr)
{
    __shared__ __align__(16) u16 P[4][16][104];
    const int band = *band_ptr;
    const int bid = blockIdx.x;
    const int tile = bid & 31;
    const int h = (bid >> 5) & 15;
    const int b = bid >> 9;
    const int w = threadIdx.x >> 6;
    const int lane = threadIdx.x & 63;
    const int fr = lane & 15, fq = lane >> 4;
    const int t0 = tile * 64 + w * 16;

    const size_t qbase = ((size_t)b * TSEQ) * 3072 + h * DHEAD;          // q cols
    const size_t kbase = qbase + 1024;                                   // k cols
    const size_t cbase = ((size_t)b * TSEQ) * DMODEL + h * DHEAD;        // ctx

    const bf16x8 aq0 = *(const bf16x8*)&qkv[qbase + (size_t)(t0 + fr) * 3072 + fq * 8];
    const bf16x8 aq1 = *(const bf16x8*)&qkv[qbase + (size_t)(t0 + fr) * 3072 + 32 + fq * 8];

    const int kb0 = t0 - 32;
    const f32x4 zero = {0.f, 0.f, 0.f, 0.f};

    f32x4 sc[5];
#pragma unroll
    for (int kt = 0; kt < 5; ++kt) {
        const int srow = kb0 + kt * 16 + fr;
        const int scl = min(max(srow, 0), TSEQ - 1);
        const bf16x8 kf0 = *(const bf16x8*)&qkv[kbase + (size_t)scl * 3072 + fq * 8];
        const bf16x8 kf1 = *(const bf16x8*)&qkv[kbase + (size_t)scl * 3072 + 32 + fq * 8];
        f32x4 a = zero;
        a = __builtin_amdgcn_mfma_f32_16x16x32_bf16(aq0, kf0, a, 0, 0, 0);
        a = __builtin_amdgcn_mfma_f32_16x16x32_bf16(aq1, kf1, a, 0, 0, 0);
        sc[kt] = a;
    }

    float mx[4], l[4];
#pragma unroll
    for (int j = 0; j < 4; ++j) mx[j] = -1e30f;
#pragma unroll
    for (int kt = 0; kt < 5; ++kt) {
        const int s = kb0 + kt * 16 + fr;
#pragma unroll
        for (int j = 0; j < 4; ++j) {
            const int tq = t0 + fq * 4 + j;
            const bool ok = (s >= 0) && (s < TSEQ) && (abs(tq - s) <= band);
            const float vv = ok ? sc[kt][j] * 0.125f : -1e30f;
            sc[kt][j] = vv;
            mx[j] = fmaxf(mx[j], vv);
        }
    }
#pragma unroll
    for (int m = 1; m <= 8; m <<= 1)
#pragma unroll
        for (int j = 0; j < 4; ++j) mx[j] = fmaxf(mx[j], __shfl_xor(mx[j], m));

#pragma unroll
    for (int j = 0; j < 4; ++j) l[j] = 0.f;
#pragma unroll
    for (int kt = 0; kt < 5; ++kt)
#pragma unroll
        for (int j = 0; j < 4; ++j) {
            const float p = __expf(sc[kt][j] - mx[j]);
            sc[kt][j] = p;
            l[j] += p;
        }
#pragma unroll
    for (int m = 1; m <= 8; m <<= 1)
#pragma unroll
        for (int j = 0; j < 4; ++j) l[j] += __shfl_xor(l[j], m);

#pragma unroll
    for (int kt = 0; kt < 5; ++kt)
#pragma unroll
        for (int j = 0; j < 4; ++j)
            P[w][fq * 4 + j][kt * 16 + fr] = f2bf(sc[kt][j]);
    {
        const short4 z4 = {0, 0, 0, 0};
        *(short4*)&P[w][fr][80 + fq * 4] = z4;
    }
    __syncthreads();

    bf16x8 pa[3];
#pragma unroll
    for (int c = 0; c < 3; ++c)
        pa[c] = *(const bf16x8*)&P[w][fr][c * 32 + fq * 8];

    const size_t vbase = ((size_t)(b * NHEAD + h) * DHEAD) * TSEQ;
    f32x4 cacc[4];
#pragma unroll
    for (int dt = 0; dt < 4; ++dt) cacc[dt] = zero;
#pragma unroll
    for (int dt = 0; dt < 4; ++dt) {
#pragma unroll
        for (int c = 0; c < 3; ++c) {
            const int s8 = kb0 + c * 32 + fq * 8;
            const int s8c = min(max(s8, 0), TSEQ - 8);
            const bf16x8 vf = *(const bf16x8*)&vT[vbase + (size_t)(dt * 16 + fr) * TSEQ + s8c];
            cacc[dt] = __builtin_amdgcn_mfma_f32_16x16x32_bf16(pa[c], vf, cacc[dt], 0, 0, 0);
        }
    }

    float rl[4];
#pragma unroll
    for (int j = 0; j < 4; ++j) rl[j] = 1.0f / l[j];
#pragma unroll
    for (int dt = 0; dt < 4; ++dt)
#pragma unroll
        for (int j = 0; j < 4; ++j)
            ctx[cbase + (size_t)(t0 + fq * 4 + j) * DMODEL + dt * 16 + fr] =
                f2bf(cacc[dt][j] * rl[j]);
}

// ---------------------------------------------------------------------------
extern "C" void kernel_launch(void* const* d_in, const int* in_sizes, int n_in,
                              void* d_out, int out_size, void* d_ws, size_t ws_size,
                              hipStream_t stream) {
    const float* x_ref  = (const float*)d_in[0];
    const float* x_mem  = (const float*)d_in[1];
    const float* ln_q_g = (const float*)d_in[2];
    const float* ln_q_b = (const float*)d_in[3];
    const float* ln_kv_g= (const float*)d_in[4];
    const float* ln_kv_b= (const float*)d_in[5];
    const float* Wq = (const float*)d_in[6];
    const float* bq = (const float*)d_in[7];
    const float* Wk = (const float*)d_in[8];
    const float* bk = (const float*)d_in[9];
    const float* Wv = (const float*)d_in[10];
    const float* bv = (const float*)d_in[11];
    const float* Wo = (const float*)d_in[12];
    const float* bo = (const float*)d_in[13];
    const float* ln_f_g = (const float*)d_in[14];
    const float* ln_f_b = (const float*)d_in[15];
    const float* W1 = (const float*)d_in[16];
    const float* b1 = (const float*)d_in[17];
    const float* W2 = (const float*)d_in[18];
    const float* b2 = (const float*)d_in[19];
    const int*  band = (const int*)d_in[20];
    float* out = (float*)d_out;

    char* ws = (char*)d_ws;
    const size_t MB = 1024 * 1024;
    if (ws_size < 128 * MB) return;
    // layout (MB):
    //  0- 6 wt_qkv [3072][1024]      6- 8 wt_o        8-16 wt_1      16-24 wt_2
    // 24-25 bqkv                    25-33 aq         33-41 akv
    // 41-65 qkvb [4096][3072]       65-73 vT         73-81 ctxb
    // 81-97 y (fp32)                97-105 hb
    // reuse: a1 [4096][4096] bf16 @25-57 (aq/akv/qkvb dead)
    //        FFN2 partials p0 @57-73 (vT/ctxb... 57-73: qkvb tail + vT, dead)
    //                      p1 @97-113 (hb dead after FFN1)
    u16*   wt_qkv = (u16*)(ws + 0 * MB);
    u16*   wt_o   = (u16*)(ws + 6 * MB);
    u16*   wt_1   = (u16*)(ws + 8 * MB);
    u16*   wt_2   = (u16*)(ws + 16 * MB);
    float* bqkv   = (float*)(ws + 24 * MB);
    u16*   aq     = (u16*)(ws + 25 * MB);
    u16*   akv    = (u16*)(ws + 33 * MB);
    u16*   qkvb   = (u16*)(ws + 41 * MB);
    u16*   vTb    = (u16*)(ws + 65 * MB);
    u16*   ctxb   = (u16*)(ws + 73 * MB);
    float* y      = (float*)(ws + 81 * MB);
    u16*   hb     = (u16*)(ws + 97 * MB);
    u16*   a1     = (u16*)(ws + 25 * MB);
    float* p0     = (float*)(ws + 57 * MB);
    float* p1     = (float*)(ws + 97 * MB);

    dim3 blk(256);
    // weight transpose-casts (Q/K/V packed into wt_qkv rows 0/1024/2048)
    tc_kernel<<<dim3(32, 32),  blk, 0, stream>>>(Wq, wt_qkv,               1024, 1024);
    tc_kernel<<<dim3(32, 32),  blk, 0, stream>>>(Wk, wt_qkv + 1024 * 1024, 1024, 1024);
    tc_kernel<<<dim3(32, 32),  blk, 0, stream>>>(Wv, wt_qkv + 2048 * 1024, 1024, 1024);
    tc_kernel<<<dim3(32, 32),  blk, 0, stream>>>(Wo, wt_o, 1024, 1024);
    tc_kernel<<<dim3(128, 32), blk, 0, stream>>>(W1, wt_1, 1024, 4096);
    tc_kernel<<<dim3(32, 128), blk, 0, stream>>>(W2, wt_2, 4096, 1024);
    biaspack_kernel<<<12, blk, 0, stream>>>(bq, bk, bv, bqkv);
    // LayerNorms -> bf16
    ln_kernel<<<MROWS, blk, 0, stream>>>(x_ref, ln_q_g, ln_q_b, aq);
    ln_kernel<<<MROWS, blk, 0, stream>>>(x_mem, ln_kv_g, ln_kv_b, akv);
    // fused QKV projection: [4096][3072], 768 blocks (3/CU)
    gemm_bt<0><<<dim3(768), blk, 0, stream>>>(aq, akv, wt_qkv, bqkv, nullptr,
                                              qkvb, nullptr, nullptr,
                                              MROWS, 3072, 1024, 1024, 24);
    // V transpose for PV fragments
    vt_kernel<<<dim3(32, 16, 2), blk, 0, stream>>>(qkvb, vTb);
    // banded MFMA attention
    battn_kernel<<<1024, blk, 0, stream>>>(qkvb, vTb, ctxb, band);
    // y = x_refined + ctx @ Wo + bo   (fp32)
    gemm_bt<2><<<dim3(256), blk, 0, stream>>>(ctxb, nullptr, wt_o, bo, x_ref,
                                              nullptr, y, nullptr,
                                              MROWS, 1024, 1024, 1024, 8);
    // LN_f(y) -> bf16
    ln_kernel<<<MROWS, blk, 0, stream>>>(y, ln_f_g, ln_f_b, hb);
    // FFN1: GELU(hb @ W1 + b1) -> a1 (bf16), 1024 blocks
    gemm_bt<1><<<dim3(1024), blk, 0, stream>>>(hb, nullptr, wt_1, b1, nullptr,
                                               a1, nullptr, nullptr,
                                               MROWS, 4096, 1024, 1024, 32);
    // FFN2 split-K=2: partials p0/p1, then reduce with bias+residual
    gemm_bt<3><<<dim3(256, 2), blk, 0, stream>>>(a1, nullptr, wt_2, nullptr, nullptr,
                                                 nullptr, p0, p1,
                                                 MROWS, 1024, 4096, 2048, 8);
    redk_kernel<<<2048, blk, 0, stream>>>(p0, p1, b2, y, out, MROWS * 1024 / 4, 1024);
}

// Round 4
// 365.623 us; speedup vs baseline: 1.8561x; 1.1165x over previous
//
#include <hip/hip_runtime.h>
#include <math.h>
#include <stdint.h>

// Problem constants (B=2, T=2048, D=1024, H=16, DH=64)
#define TSEQ   2048
#define DMODEL 1024
#define NHEAD  16
#define DHEAD  64
#define MROWS  4096   // B*T

typedef short bf16x8 __attribute__((ext_vector_type(8)));
typedef float f32x4  __attribute__((ext_vector_type(4)));
typedef uint64_t u64x2 __attribute__((ext_vector_type(2)));
typedef unsigned short u16;

typedef __attribute__((address_space(3))) unsigned int lds_u32_t;
typedef __attribute__((address_space(1))) unsigned int glb_u32_t;

static __device__ __forceinline__ u16 f2bf(float f) {
    unsigned u = __float_as_uint(f);
    u += 0x7FFFu + ((u >> 16) & 1u);   // round-to-nearest-even
    return (u16)(u >> 16);
}
static __device__ __forceinline__ float bf2f(u16 h) {
    return __uint_as_float(((unsigned)h) << 16);
}

// ---------------------------------------------------------------------------
// Transpose + cast: W[K][N] fp32  ->  Wt[N][K] bf16-bits
// ---------------------------------------------------------------------------
__global__ __launch_bounds__(256) void tc_kernel(
    const float* __restrict__ W, u16* __restrict__ Wt, int K, int N)
{
    __shared__ u16 tile[32][33];
    const int n0 = blockIdx.x * 32, k0 = blockIdx.y * 32;
    const int t = threadIdx.x;
    const int tx = t & 31, ty = t >> 5;           // 32 x 8
#pragma unroll
    for (int i = 0; i < 4; ++i) {
        int kk = ty + i * 8;
        tile[kk][tx] = f2bf(W[(size_t)(k0 + kk) * N + n0 + tx]);
    }
    __syncthreads();
#pragma unroll
    for (int i = 0; i < 4; ++i) {
        int nn = ty + i * 8;
        Wt[(size_t)(n0 + nn) * K + k0 + tx] = tile[tx][nn];
    }
}

// ---------------------------------------------------------------------------
// Pack 3 bias vectors (1024 each) into one 3072 fp32 vector
// ---------------------------------------------------------------------------
__global__ __launch_bounds__(256) void biaspack_kernel(
    const float* __restrict__ bq, const float* __restrict__ bk,
    const float* __restrict__ bv, float* __restrict__ o)
{
    const int i = blockIdx.x * 256 + threadIdx.x;
    if (i < 1024) o[i] = bq[i];
    else if (i < 2048) o[i] = bk[i - 1024];
    else if (i < 3072) o[i] = bv[i - 2048];
}

// ---------------------------------------------------------------------------
// bf16 transpose of V section: qkv[b*T + t][2048 + hd] -> vT[(b*16+h)*64+d][t]
// ---------------------------------------------------------------------------
__global__ __launch_bounds__(256) void vt_kernel(
    const u16* __restrict__ qkv, u16* __restrict__ vT)
{
    __shared__ __align__(16) u16 tile[64][72];
    const int bb = blockIdx.z;
    const int t0 = blockIdx.x * 64;
    const int c0 = blockIdx.y * 64;     // hd
    const int tid = threadIdx.x;
    const int r = tid >> 2;             // 0..63
    const int c = (tid & 3) * 16;       // 0,16,32,48
    const u16* src = qkv + (size_t)(bb * TSEQ + t0 + r) * 3072 + 2048 + c0 + c;
    *(bf16x8*)&tile[r][c]     = *(const bf16x8*)(src);
    *(bf16x8*)&tile[r][c + 8] = *(const bf16x8*)(src + 8);
    __syncthreads();
    u16 o[16];
#pragma unroll
    for (int j = 0; j < 16; ++j) o[j] = tile[c + j][r];
    u16* dst = vT + (size_t)(bb * 1024 + c0 + r) * TSEQ + t0 + c;
    *(bf16x8*)dst       = *(bf16x8*)&o[0];
    *(bf16x8*)(dst + 8) = *(bf16x8*)&o[8];
}

// ---------------------------------------------------------------------------
// LayerNorm(fp32 row of 1024) -> bf16 row. One block (256 thr) per row.
// ---------------------------------------------------------------------------
__global__ __launch_bounds__(256) void ln_kernel(
    const float* __restrict__ x, const float* __restrict__ g,
    const float* __restrict__ b, u16* __restrict__ out)
{
    const int row = blockIdx.x;
    const int t = threadIdx.x;
    const float4 v = ((const float4*)(x + (size_t)row * DMODEL))[t];
    float s  = v.x + v.y + v.z + v.w;
    float s2 = v.x * v.x + v.y * v.y + v.z * v.z + v.w * v.w;
#pragma unroll
    for (int m = 32; m >= 1; m >>= 1) { s += __shfl_xor(s, m); s2 += __shfl_xor(s2, m); }
    __shared__ float ps[4], ps2[4];
    if ((t & 63) == 0) { ps[t >> 6] = s; ps2[t >> 6] = s2; }
    __syncthreads();
    const float S  = ps[0] + ps[1] + ps[2] + ps[3];
    const float S2 = ps2[0] + ps2[1] + ps2[2] + ps2[3];
    const float mean = S * (1.0f / DMODEL);
    const float var  = S2 * (1.0f / DMODEL) - mean * mean;
    const float rstd = rsqrtf(var + 1e-5f);
    const float4 gg = ((const float4*)g)[t];
    const float4 bb = ((const float4*)b)[t];
    u16 o[4];
    o[0] = f2bf((v.x - mean) * rstd * gg.x + bb.x);
    o[1] = f2bf((v.y - mean) * rstd * gg.y + bb.y);
    o[2] = f2bf((v.z - mean) * rstd * gg.z + bb.z);
    o[3] = f2bf((v.w - mean) * rstd * gg.w + bb.w);
    *(short4*)(out + (size_t)row * DMODEL + t * 4) = *(short4*)o;
}

// ---------------------------------------------------------------------------
// GEMM: C[M][N] = A[M][K] * Wt[N][K]^T (+bias) (+epilogue)
//   EPI 0: +bias, store bf16 (LDS-coalesced)
//   EPI 1: +bias, exact GELU, store bf16 (LDS-coalesced)
//   EPI 2: +bias, += resid (fp32), store fp32
//   EPI 3: split-K partial, no bias, fp32 to (blockIdx.y ? Cf2 : Cf)
// 128x128 tile, BK=32, 4 waves. T3-minimum 2-deep pipeline: double-buffered
// LDS, stage(t+2) issued at end of iter t, counted s_waitcnt vmcnt(4) + raw
// s_barrier (never vmcnt(0) in main loop). 2-D XCD tile chunking for L2.
// ---------------------------------------------------------------------------
template <int EPI>
__global__ __launch_bounds__(256) void gemm_bt(
    const u16* __restrict__ A, const u16* __restrict__ A2,
    const u16* __restrict__ Wt,
    const float* __restrict__ bias, const float* __restrict__ resid,
    u16* __restrict__ Cb, float* __restrict__ Cf, float* __restrict__ Cf2,
    int N, int K, int kl, int gx, int cx)
{
    extern __shared__ __align__(16) char smem[];   // 2x16KB stage | 33792B C-tile

    // 2-D XCD chunking: xcd = bid&7 (HW round-robin), each XCD owns an
    // sx x sy rectangle of 128-tiles (perf-only heuristic, bijective).
    const int bid = blockIdx.x;
    const int xcd = bid & 7, jj = bid >> 3;
    const int sx = gx / cx;
    const int sy = (gridDim.x >> 3) / sx;
    const int xr = xcd / cx, xc = xcd % cx;
    const int jr = jj / sx, jc = jj % sx;
    const int m0 = (xr * sy + jr) * 128;
    const int n0 = (xc * sx + jc) * 128;
    const int kofs = blockIdx.y * kl;

    const int t = threadIdx.x;
    const int lane = t & 63;
    const int wv = t >> 6;
    const int wr = wv >> 1, wc = wv & 1;

    const u16* Ause = (A2 != nullptr && n0 >= 1024) ? A2 : A;

    const int strow = t >> 2;            // 0..63
    const int stcol = (t & 3) * 8;
    const u16* gA  = Ause + (size_t)(m0 + strow) * K + kofs + stcol;
    const u16* gA2 = gA + (size_t)64 * K;
    const u16* gB  = Wt + (size_t)(n0 + strow) * K + kofs + stcol;
    const u16* gB2 = gB + (size_t)64 * K;

#define STAGE(bufi, k0) do {                                                            \
    char* _b = smem + (bufi) * 16384 + wv * 1024;                                       \
    __builtin_amdgcn_global_load_lds((const glb_u32_t*)(gA  + (k0)), (lds_u32_t*)(_b),          16, 0, 0); \
    __builtin_amdgcn_global_load_lds((const glb_u32_t*)(gA2 + (k0)), (lds_u32_t*)(_b + 4096),  16, 0, 0); \
    __builtin_amdgcn_global_load_lds((const glb_u32_t*)(gB  + (k0)), (lds_u32_t*)(_b + 8192),  16, 0, 0); \
    __builtin_amdgcn_global_load_lds((const glb_u32_t*)(gB2 + (k0)), (lds_u32_t*)(_b + 12288), 16, 0, 0); \
} while (0)

    f32x4 zero = {0.f, 0.f, 0.f, 0.f};
    f32x4 acc[4][4];
#pragma unroll
    for (int mi = 0; mi < 4; ++mi)
#pragma unroll
        for (int ni = 0; ni < 4; ++ni) acc[mi][ni] = zero;

    const int fr = lane & 15, fq = lane >> 4;
    const int nk = kl >> 5;

    // prologue: 2 tiles in flight
    STAGE(0, 0);
    STAGE(1, 32);

    for (int kt = 0; kt < nk; ++kt) {
        const int cur = kt & 1;
        if (kt < nk - 1) { asm volatile("s_waitcnt vmcnt(4)" ::: "memory"); }
        else             { asm volatile("s_waitcnt vmcnt(0)" ::: "memory"); }
        __builtin_amdgcn_s_barrier();          // buf[cur] staged for all waves

        const u16* As_ = (const u16*)smem + cur * 8192;
        const u16* Bs_ = As_ + 4096;
        bf16x8 af[4], bfr[4];
#pragma unroll
        for (int mi = 0; mi < 4; ++mi)
            af[mi] = *(const bf16x8*)&As_[(wr * 64 + mi * 16 + fr) * 32 + fq * 8];
#pragma unroll
        for (int ni = 0; ni < 4; ++ni)
            bfr[ni] = *(const bf16x8*)&Bs_[(wc * 64 + ni * 16 + fr) * 32 + fq * 8];

        __builtin_amdgcn_s_setprio(1);
#pragma unroll
        for (int mi = 0; mi < 4; ++mi)
#pragma unroll
            for (int ni = 0; ni < 4; ++ni)
                acc[mi][ni] = __builtin_amdgcn_mfma_f32_16x16x32_bf16(af[mi], bfr[ni], acc[mi][ni], 0, 0, 0);
        __builtin_amdgcn_s_setprio(0);
        __builtin_amdgcn_sched_barrier(0);     // pin reads+MFMA before bar2
        __builtin_amdgcn_s_barrier();          // all reads of buf[cur] done
        if (kt + 2 < nk) STAGE(cur, (kt + 2) << 5);
    }
#undef STAGE

    if (EPI <= 1) {
        // coalesced bf16 store via LDS C-tile (stride 132 u16 = 264B rows)
        u16* cs = (u16*)smem;
#pragma unroll
        for (int ni = 0; ni < 4; ++ni) {
            const int col = wc * 64 + ni * 16 + fr;
            const float bv = bias[n0 + col];
#pragma unroll
            for (int mi = 0; mi < 4; ++mi) {
#pragma unroll
                for (int j = 0; j < 4; ++j) {
                    const int row = wr * 64 + mi * 16 + fq * 4 + j;
                    float val = acc[mi][ni][j] + bv;
                    if (EPI == 1)
                        val = 0.5f * val * (1.0f + erff(val * 0.70710678118654752f));
                    cs[row * 132 + col] = f2bf(val);
                }
            }
        }
        __syncthreads();
        const int rr = t >> 4, cc = (t & 15) * 8;
#pragma unroll
        for (int c8 = 0; c8 < 8; ++c8) {
            const int row = c8 * 16 + rr;
            const uint64_t lo = *(const uint64_t*)&cs[row * 132 + cc];
            const uint64_t hi = *(const uint64_t*)&cs[row * 132 + cc + 4];
            u64x2 v; v.x = lo; v.y = hi;
            *(u64x2*)&Cb[(size_t)(m0 + row) * N + n0 + cc] = v;
        }
    } else {
        float* Cpart = (EPI == 3) ? (blockIdx.y ? Cf2 : Cf) : Cf;
#pragma unroll
        for (int ni = 0; ni < 4; ++ni) {
            const int col = n0 + wc * 64 + ni * 16 + fr;
            const float bv = (EPI == 3) ? 0.f : bias[col];
#pragma unroll
            for (int mi = 0; mi < 4; ++mi) {
#pragma unroll
                for (int j = 0; j < 4; ++j) {
                    const int row = m0 + wr * 64 + mi * 16 + fq * 4 + j;
                    float val = acc[mi][ni][j] + bv;
                    if (EPI == 2)
                        Cf[(size_t)row * N + col] = val + resid[(size_t)row * N + col];
                    else
                        Cpart[(size_t)row * N + col] = val;
                }
            }
        }
    }
}

// ---------------------------------------------------------------------------
// Split-K reduce: out = p0 + p1 + bias + resid  (fp32, vectorized)
// ---------------------------------------------------------------------------
__global__ __launch_bounds__(256) void redk_kernel(
    const float* __restrict__ p0, const float* __restrict__ p1,
    const float* __restrict__ bias, const float* __restrict__ resid,
    float* __restrict__ out, int n4, int ncols)
{
    const int stride = gridDim.x * 256;
    for (int i = blockIdx.x * 256 + threadIdx.x; i < n4; i += stride) {
        const float4 a = ((const float4*)p0)[i];
        const float4 b = ((const float4*)p1)[i];
        const float4 r = ((const float4*)resid)[i];
        const float4 bb = *(const float4*)&bias[(i * 4) & (ncols - 1)];
        float4 o;
        o.x = a.x + b.x + bb.x + r.x;
        o.y = a.y + b.y + bb.y + r.y;
        o.z = a.z + b.z + bb.z + r.z;
        o.w = a.w + b.w + bb.w + r.w;
        ((float4*)out)[i] = o;
    }
}

// ---------------------------------------------------------------------------
// Banded attention via MFMA. One wave = 16 queries x 80-key aligned window
// (supports band <= 32). q,k read from fused qkv [4096][3072]; ctx -> [4096][1024].
// ---------------------------------------------------------------------------
__global__ __launch_bounds__(256) void battn_kernel(
    const u16* __restrict__ qkv, const u16* __restrict__ vT,
    u16* __restrict__ ctx, const int* __restrict__ band_ptr)
{
    __shared__ __align__(16) u16 P[4][16][104];
    const int band = *band_ptr;
    const int bid = blockIdx.x;
    const int tile = bid & 31;
    const int h = (bid >> 5) & 15;
    const int b = bid >> 9;
    const int w = threadIdx.x >> 6;
    const int lane = threadIdx.x & 63;
    const int fr = lane & 15, fq = lane >> 4;
    const int t0 = tile * 64 + w * 16;

    const size_t qbase = ((size_t)b * TSEQ) * 3072 + h * DHEAD;          // q cols
    const size_t kbase = qbase + 1024;                                   // k cols
    const size_t cbase = ((size_t)b * TSEQ) * DMODEL + h * DHEAD;        // ctx

    const bf16x8 aq0 = *(const bf16x8*)&qkv[qbase + (size_t)(t0 + fr) * 3072 + fq * 8];
    const bf16x8 aq1 = *(const bf16x8*)&qkv[qbase + (size_t)(t0 + fr) * 3072 + 32 + fq * 8];

    const int kb0 = t0 - 32;
    const f32x4 zero = {0.f, 0.f, 0.f, 0.f};

    f32x4 sc[5];
#pragma unroll
    for (int kt = 0; kt < 5; ++kt) {
        const int srow = kb0 + kt * 16 + fr;
        const int scl = min(max(srow, 0), TSEQ - 1);
        const bf16x8 kf0 = *(const bf16x8*)&qkv[kbase + (size_t)scl * 3072 + fq * 8];
        const bf16x8 kf1 = *(const bf16x8*)&qkv[kbase + (size_t)scl * 3072 + 32 + fq * 8];
        f32x4 a = zero;
        a = __builtin_amdgcn_mfma_f32_16x16x32_bf16(aq0, kf0, a, 0, 0, 0);
        a = __builtin_amdgcn_mfma_f32_16x16x32_bf16(aq1, kf1, a, 0, 0, 0);
        sc[kt] = a;
    }

    float mx[4], l[4];
#pragma unroll
    for (int j = 0; j < 4; ++j) mx[j] = -1e30f;
#pragma unroll
    for (int kt = 0; kt < 5; ++kt) {
        const int s = kb0 + kt * 16 + fr;
#pragma unroll
        for (int j = 0; j < 4; ++j) {
            const int tq = t0 + fq * 4 + j;
            const bool ok = (s >= 0) && (s < TSEQ) && (abs(tq - s) <= band);
            const float vv = ok ? sc[kt][j] * 0.125f : -1e30f;
            sc[kt][j] = vv;
            mx[j] = fmaxf(mx[j], vv);
        }
    }
#pragma unroll
    for (int m = 1; m <= 8; m <<= 1)
#pragma unroll
        for (int j = 0; j < 4; ++j) mx[j] = fmaxf(mx[j], __shfl_xor(mx[j], m));

#pragma unroll
    for (int j = 0; j < 4; ++j) l[j] = 0.f;
#pragma unroll
    for (int kt = 0; kt < 5; ++kt)
#pragma unroll
        for (int j = 0; j < 4; ++j) {
            const float p = __expf(sc[kt][j] - mx[j]);
            sc[kt][j] = p;
            l[j] += p;
        }
#pragma unroll
    for (int m = 1; m <= 8; m <<= 1)
#pragma unroll
        for (int j = 0; j < 4; ++j) l[j] += __shfl_xor(l[j], m);

#pragma unroll
    for (int kt = 0; kt < 5; ++kt)
#pragma unroll
        for (int j = 0; j < 4; ++j)
            P[w][fq * 4 + j][kt * 16 + fr] = f2bf(sc[kt][j]);
    {
        const short4 z4 = {0, 0, 0, 0};
        *(short4*)&P[w][fr][80 + fq * 4] = z4;
    }
    __syncthreads();

    bf16x8 pa[3];
#pragma unroll
    for (int c = 0; c < 3; ++c)
        pa[c] = *(const bf16x8*)&P[w][fr][c * 32 + fq * 8];

    const size_t vbase = ((size_t)(b * NHEAD + h) * DHEAD) * TSEQ;
    f32x4 cacc[4];
#pragma unroll
    for (int dt = 0; dt < 4; ++dt) cacc[dt] = zero;
#pragma unroll
    for (int dt = 0; dt < 4; ++dt) {
#pragma unroll
        for (int c = 0; c < 3; ++c) {
            const int s8 = kb0 + c * 32 + fq * 8;
            const int s8c = min(max(s8, 0), TSEQ - 8);
            const bf16x8 vf = *(const bf16x8*)&vT[vbase + (size_t)(dt * 16 + fr) * TSEQ + s8c];
            cacc[dt] = __builtin_amdgcn_mfma_f32_16x16x32_bf16(pa[c], vf, cacc[dt], 0, 0, 0);
        }
    }

    float rl[4];
#pragma unroll
    for (int j = 0; j < 4; ++j) rl[j] = 1.0f / l[j];
#pragma unroll
    for (int dt = 0; dt < 4; ++dt)
#pragma unroll
        for (int j = 0; j < 4; ++j)
            ctx[cbase + (size_t)(t0 + fq * 4 + j) * DMODEL + dt * 16 + fr] =
                f2bf(cacc[dt][j] * rl[j]);
}

// ---------------------------------------------------------------------------
extern "C" void kernel_launch(void* const* d_in, const int* in_sizes, int n_in,
                              void* d_out, int out_size, void* d_ws, size_t ws_size,
                              hipStream_t stream) {
    const float* x_ref  = (const float*)d_in[0];
    const float* x_mem  = (const float*)d_in[1];
    const float* ln_q_g = (const float*)d_in[2];
    const float* ln_q_b = (const float*)d_in[3];
    const float* ln_kv_g= (const float*)d_in[4];
    const float* ln_kv_b= (const float*)d_in[5];
    const float* Wq = (const float*)d_in[6];
    const float* bq = (const float*)d_in[7];
    const float* Wk = (const float*)d_in[8];
    const float* bk = (const float*)d_in[9];
    const float* Wv = (const float*)d_in[10];
    const float* bv = (const float*)d_in[11];
    const float* Wo = (const float*)d_in[12];
    const float* bo = (const float*)d_in[13];
    const float* ln_f_g = (const float*)d_in[14];
    const float* ln_f_b = (const float*)d_in[15];
    const float* W1 = (const float*)d_in[16];
    const float* b1 = (const float*)d_in[17];
    const float* W2 = (const float*)d_in[18];
    const float* b2 = (const float*)d_in[19];
    const int*  band = (const int*)d_in[20];
    float* out = (float*)d_out;

    char* ws = (char*)d_ws;
    const size_t MB = 1024 * 1024;
    if (ws_size < 128 * MB) return;
    u16*   wt_qkv = (u16*)(ws + 0 * MB);
    u16*   wt_o   = (u16*)(ws + 6 * MB);
    u16*   wt_1   = (u16*)(ws + 8 * MB);
    u16*   wt_2   = (u16*)(ws + 16 * MB);
    float* bqkv   = (float*)(ws + 24 * MB);
    u16*   aq     = (u16*)(ws + 25 * MB);
    u16*   akv    = (u16*)(ws + 33 * MB);
    u16*   qkvb   = (u16*)(ws + 41 * MB);
    u16*   vTb    = (u16*)(ws + 65 * MB);
    u16*   ctxb   = (u16*)(ws + 73 * MB);
    float* y      = (float*)(ws + 81 * MB);
    u16*   hb     = (u16*)(ws + 97 * MB);
    u16*   a1     = (u16*)(ws + 25 * MB);
    float* p0     = (float*)(ws + 57 * MB);
    float* p1     = (float*)(ws + 97 * MB);

    dim3 blk(256);
    const size_t SM_GEMM = 32768;   // 2x16KB stage buffers
    const size_t SM_BF16 = 33792;   // max(32KB, 128x132x2 C-tile)

    tc_kernel<<<dim3(32, 32),  blk, 0, stream>>>(Wq, wt_qkv,               1024, 1024);
    tc_kernel<<<dim3(32, 32),  blk, 0, stream>>>(Wk, wt_qkv + 1024 * 1024, 1024, 1024);
    tc_kernel<<<dim3(32, 32),  blk, 0, stream>>>(Wv, wt_qkv + 2048 * 1024, 1024, 1024);
    tc_kernel<<<dim3(32, 32),  blk, 0, stream>>>(Wo, wt_o, 1024, 1024);
    tc_kernel<<<dim3(128, 32), blk, 0, stream>>>(W1, wt_1, 1024, 4096);
    tc_kernel<<<dim3(32, 128), blk, 0, stream>>>(W2, wt_2, 4096, 1024);
    biaspack_kernel<<<12, blk, 0, stream>>>(bq, bk, bv, bqkv);
    ln_kernel<<<MROWS, blk, 0, stream>>>(x_ref, ln_q_g, ln_q_b, aq);
    ln_kernel<<<MROWS, blk, 0, stream>>>(x_mem, ln_kv_g, ln_kv_b, akv);
    // fused QKV projection: [4096][3072]; tiles 32y x 24x; XCD grid 4y x 2x
    gemm_bt<0><<<dim3(768), blk, SM_BF16, stream>>>(aq, akv, wt_qkv, bqkv, nullptr,
                                                    qkvb, nullptr, nullptr,
                                                    3072, 1024, 1024, 24, 2);
    vt_kernel<<<dim3(32, 16, 2), blk, 0, stream>>>(qkvb, vTb);
    battn_kernel<<<1024, blk, 0, stream>>>(qkvb, vTb, ctxb, band);
    // y = x_refined + ctx @ Wo + bo; tiles 32y x 8x; XCD grid 8y x 1x
    gemm_bt<2><<<dim3(256), blk, SM_GEMM, stream>>>(ctxb, nullptr, wt_o, bo, x_ref,
                                                    nullptr, y, nullptr,
                                                    1024, 1024, 1024, 8, 1);
    ln_kernel<<<MROWS, blk, 0, stream>>>(y, ln_f_g, ln_f_b, hb);
    // FFN1: GELU(hb @ W1 + b1); tiles 32y x 32x; XCD grid 4y x 2x
    gemm_bt<1><<<dim3(1024), blk, SM_BF16, stream>>>(hb, nullptr, wt_1, b1, nullptr,
                                                     a1, nullptr, nullptr,
                                                     4096, 1024, 1024, 32, 2);
    // FFN2 split-K=2; tiles 32y x 8x; XCD grid 8y x 1x
    gemm_bt<3><<<dim3(256, 2), blk, SM_GEMM, stream>>>(a1, nullptr, wt_2, nullptr, nullptr,
                                                       nullptr, p0, p1,
                                                       1024, 4096, 2048, 8, 1);
    redk_kernel<<<2048, blk, 0, stream>>>(p0, p1, b2, y, out, MROWS * 1024 / 4, 1024);
}